// Round 4
// baseline (68.358 us; speedup 1.0000x reference)
//
#include <hip/hip_runtime.h>
#include <hip/hip_bf16.h>

#define STUN   50000
#define BATCH  4096
#define LOG2E  1.4426950408889634f

__device__ __forceinline__ float fexp2(float x){ return __builtin_amdgcn_exp2f(x); }
__device__ __forceinline__ float frcp (float x){ return __builtin_amdgcn_rcpf(x); }
__device__ __forceinline__ float fsig (float x){ return frcp(1.0f + fexp2(-LOG2E * x)); }
// pre-scaled domain: x already multiplied by -log2e
__device__ __forceinline__ float fsigp(float x){ return frcp(1.0f + fexp2(x)); }

// ---------------------------------------------------------------------------
// K0: weight repack (float4-interleaved) + A-matrix precompute.
//   kle4 [u4=16][idx=128][4]  = kle[idx][u4*4+c]
//   fc1i/fc2i [u4=48][128][4] = fcW[idx][u4*4+c]
//   W1ai/W2ai [u4=32][128][4] = W[idx][u4*4+c]        (the 'a' half, u<128)
//   A1KJ/A2KJ [k=128][j=128]  = -log2e * sum_t kle[k][t]*W[j][128+t]
// grid 432 blocks x 128 threads
// ---------------------------------------------------------------------------
__global__ __launch_bounds__(128) void k_pre(
    const float* __restrict__ kle,
    const float* __restrict__ W1,
    const float* __restrict__ W2,
    const float* __restrict__ fc1_W,
    const float* __restrict__ fc2_W,
    float* __restrict__ kle4,
    float* __restrict__ fc1i,
    float* __restrict__ fc2i,
    float* __restrict__ W1ai,
    float* __restrict__ W2ai,
    float* __restrict__ A1KJ,
    float* __restrict__ A2KJ)
{
    const int bid = blockIdx.x;
    const int t   = threadIdx.x;   // 0..127
    if (bid < 16) {
        const int u4 = bid;
        float4 v;
        v.x = kle[t * 64 + u4 * 4 + 0];
        v.y = kle[t * 64 + u4 * 4 + 1];
        v.z = kle[t * 64 + u4 * 4 + 2];
        v.w = kle[t * 64 + u4 * 4 + 3];
        *(float4*)&kle4[(u4 * 128 + t) * 4] = v;
    } else if (bid < 64) {
        const int u4 = bid - 16;
        float4 v;
        v.x = fc1_W[t * 192 + u4 * 4 + 0];
        v.y = fc1_W[t * 192 + u4 * 4 + 1];
        v.z = fc1_W[t * 192 + u4 * 4 + 2];
        v.w = fc1_W[t * 192 + u4 * 4 + 3];
        *(float4*)&fc1i[(u4 * 128 + t) * 4] = v;
    } else if (bid < 112) {
        const int u4 = bid - 64;
        float4 v;
        v.x = fc2_W[t * 192 + u4 * 4 + 0];
        v.y = fc2_W[t * 192 + u4 * 4 + 1];
        v.z = fc2_W[t * 192 + u4 * 4 + 2];
        v.w = fc2_W[t * 192 + u4 * 4 + 3];
        *(float4*)&fc2i[(u4 * 128 + t) * 4] = v;
    } else if (bid < 144) {
        const int u4 = bid - 112;
        float4 v;
        v.x = W1[t * 192 + u4 * 4 + 0];
        v.y = W1[t * 192 + u4 * 4 + 1];
        v.z = W1[t * 192 + u4 * 4 + 2];
        v.w = W1[t * 192 + u4 * 4 + 3];
        *(float4*)&W1ai[(u4 * 128 + t) * 4] = v;
    } else if (bid < 176) {
        const int u4 = bid - 144;
        float4 v;
        v.x = W2[t * 192 + u4 * 4 + 0];
        v.y = W2[t * 192 + u4 * 4 + 1];
        v.z = W2[t * 192 + u4 * 4 + 2];
        v.w = W2[t * 192 + u4 * 4 + 3];
        *(float4*)&W2ai[(u4 * 128 + t) * 4] = v;
    } else if (bid < 304) {
        const int j = bid - 176;          // lane t = k
        float acc = 0.f;
        #pragma unroll
        for (int u4 = 0; u4 < 16; ++u4) {
            const float4 kv = *(const float4*)&kle[t * 64 + u4 * 4];
            const float4 wv = *(const float4*)&W1[j * 192 + 128 + u4 * 4];
            acc += kv.x * wv.x + kv.y * wv.y + kv.z * wv.z + kv.w * wv.w;
        }
        A1KJ[t * 128 + j] = -LOG2E * acc;
    } else {
        const int j = bid - 304;
        float acc = 0.f;
        #pragma unroll
        for (int u4 = 0; u4 < 16; ++u4) {
            const float4 kv = *(const float4*)&kle[t * 64 + u4 * 4];
            const float4 wv = *(const float4*)&W2[j * 192 + 128 + u4 * 4];
            acc += kv.x * wv.x + kv.y * wv.y + kv.z * wv.z + kv.w * wv.w;
        }
        A2KJ[t * 128 + j] = -LOG2E * acc;
    }
}

// ---------------------------------------------------------------------------
// K_FUSED: prep (s1/s2 in LDS) + main sigmoid loop + reduction.
// 512 threads, 8 batch elems/block, grid 512.
// Prep: threads 0..255 as before (half=t>>7, idx=t&127), acc[8].
// Compute: wave w -> k = kk + (w>=4)*64, b-pair = {2*(w&3), 2*(w&3)+1};
//          a1/a2 float4 loaded once, reused for both b's.
// LDS: 64KB union(prep, sA) + 8KB sh_s + sW3 + red ~= 73KB -> 2 blocks/CU.
// ---------------------------------------------------------------------------
__global__ __launch_bounds__(512, 4) void k_fused(
    const int*   __restrict__ stu_id,
    const int*   __restrict__ exer_id,
    const float* __restrict__ student_emb,   // (2*50000, 64) flat
    const float* __restrict__ prompt_stu,    // (50000, 64)
    const float* __restrict__ k_diff,        // (20000, 64)
    const float* __restrict__ s_exer,        // (2, 64)
    const float* __restrict__ kle4,
    const float* __restrict__ fc1i,
    const float* __restrict__ fc2i,
    const float* __restrict__ W1ai,
    const float* __restrict__ W2ai,
    const float* __restrict__ fc1_b,
    const float* __restrict__ fc2_b,
    const float* __restrict__ A1KJ,   // (128 k, 128 j), pre-scaled by -log2e
    const float* __restrict__ A2KJ,
    const float* __restrict__ W3,
    const float* __restrict__ b3,
    const float* __restrict__ kn,
    float* __restrict__ out)
{
    __shared__ __align__(16) float smem[16384];   // 64 KB union region
    float (*sh_in)[64][8]   = (float(*)[64][8])  smem;           // [4][64][8]
    float (*sh_old)[128][8] = (float(*)[128][8])(smem + 2048);   // [2][128][8]
    float (*sh_e)[128][8]   = (float(*)[128][8])(smem + 4096);   // [2][128][8]
    float* sA1 = smem;            // [128][16 f4-units], swizzled (after prep)
    float* sA2 = smem + 8192;

    __shared__ float sh_s[2][8][128];
    __shared__ float sW3[128];
    __shared__ float red_o[8][2];
    __shared__ float red_k[8][2];

    const int t  = threadIdx.x;           // 0..511
    const int b0 = blockIdx.x * 8;

    // ---- gather phase: 64 threads per local batch elem, coalesced ----
    {
        const int g   = t >> 6;
        const int u   = t & 63;
        const int sid = stu_id[b0 + g];
        const int eid = exer_id[b0 + g];
        const int er  = (eid >= 10000) ? 1 : 0;
        sh_in[0][u][g] = student_emb[sid * 64 + u];
        sh_in[1][u][g] = fsig(k_diff[eid * 64 + u]);
        sh_in[2][u][g] = prompt_stu[(sid % STUN) * 64 + u];
        sh_in[3][u][g] = fsig(s_exer[er * 64 + u]);
    }
    if (t < 32) *(float4*)&sW3[t * 4] = *(const float4*)&W3[t * 4];
    __syncthreads();

    const int half = (t >> 7) & 1;
    const int idx  = t & 127;

#define FMA8(xbase) { \
        const float4 x0 = *(const float4*)&(xbase)[0]; \
        const float4 x1 = *(const float4*)&(xbase)[4]; \
        acc[0] += wv * x0.x; acc[1] += wv * x0.y; acc[2] += wv * x0.z; acc[3] += wv * x0.w; \
        acc[4] += wv * x1.x; acc[5] += wv * x1.y; acc[6] += wv * x1.z; acc[7] += wv * x1.w; }

    // ---- stage 1: old[k] = sig( dot(row, kle[k]) ) ----
    if (t < 256) {
        float acc[8];
        #pragma unroll
        for (int b = 0; b < 8; ++b) acc[b] = 0.f;
        #pragma unroll 4
        for (int u4 = 0; u4 < 16; ++u4) {
            const float4 w4 = *(const float4*)&kle4[(u4 * 128 + idx) * 4];
            { const float wv = w4.x; FMA8(sh_in[half][u4*4+0]); }
            { const float wv = w4.y; FMA8(sh_in[half][u4*4+1]); }
            { const float wv = w4.z; FMA8(sh_in[half][u4*4+2]); }
            { const float wv = w4.w; FMA8(sh_in[half][u4*4+3]); }
        }
        #pragma unroll
        for (int b = 0; b < 8; ++b) sh_old[half][idx][b] = fsig(acc[b]);
    }
    __syncthreads();

    // ---- stage 2: e[i] = sig( [p, old] @ fcW[i] + fcb[i] ) ----
    if (t < 256) {
        const float* fcT = half ? fc2i : fc1i;
        const float* fcb = half ? fc2_b : fc1_b;
        float acc[8];
        #pragma unroll
        for (int b = 0; b < 8; ++b) acc[b] = 0.f;
        #pragma unroll 4
        for (int u4 = 0; u4 < 16; ++u4) {
            const float4 w4 = *(const float4*)&fcT[(u4 * 128 + idx) * 4];
            { const float wv = w4.x; FMA8(sh_in[2+half][u4*4+0]); }
            { const float wv = w4.y; FMA8(sh_in[2+half][u4*4+1]); }
            { const float wv = w4.z; FMA8(sh_in[2+half][u4*4+2]); }
            { const float wv = w4.w; FMA8(sh_in[2+half][u4*4+3]); }
        }
        #pragma unroll 4
        for (int u4 = 16; u4 < 48; ++u4) {
            const float4 w4 = *(const float4*)&fcT[(u4 * 128 + idx) * 4];
            const int uo = (u4 - 16) * 4;
            { const float wv = w4.x; FMA8(sh_old[half][uo+0]); }
            { const float wv = w4.y; FMA8(sh_old[half][uo+1]); }
            { const float wv = w4.z; FMA8(sh_old[half][uo+2]); }
            { const float wv = w4.w; FMA8(sh_old[half][uo+3]); }
        }
        const float bias = fcb[idx];
        #pragma unroll
        for (int b = 0; b < 8; ++b) sh_e[half][idx][b] = fsig(acc[b] + bias);
    }
    __syncthreads();

    // ---- stage 3: s[j] = -log2e * dot(e, Wa[j]) -> sh_s ----
    if (t < 256) {
        const float* WT = half ? W2ai : W1ai;
        float acc[8];
        #pragma unroll
        for (int b = 0; b < 8; ++b) acc[b] = 0.f;
        #pragma unroll 4
        for (int u4 = 0; u4 < 32; ++u4) {
            const float4 w4 = *(const float4*)&WT[(u4 * 128 + idx) * 4];
            { const float wv = w4.x; FMA8(sh_e[half][u4*4+0]); }
            { const float wv = w4.y; FMA8(sh_e[half][u4*4+1]); }
            { const float wv = w4.z; FMA8(sh_e[half][u4*4+2]); }
            { const float wv = w4.w; FMA8(sh_e[half][u4*4+3]); }
        }
        #pragma unroll
        for (int b = 0; b < 8; ++b) sh_s[half][b][idx] = -LOG2E * acc[b];
    }
#undef FMA8

    // ---- main loop: wave w -> one k per lane, two batch elems ----
    const int w   = t >> 6;               // wave id
    const int kk  = t & 63;
    const int kk2 = kk + ((w >= 4) ? 64 : 0);
    const int i0  = (w & 3) * 2;          // local b-pair base
    const float bb3 = b3[0];

    float acc0 = 0.f, acc1 = 0.f;         // acc per local batch elem i0, i0+1

    for (int p = 0; p < 2; ++p) {
        __syncthreads();                  // prep area / previous tile safe to overwrite
        // stage 64 j-columns of A1KJ/A2KJ, swizzled units (conflict-free b128)
        #pragma unroll
        for (int i = 0; i < 4; ++i) {
            const int gu = i * 512 + t;   // unit id 0..2047
            const int k  = gu >> 4;
            const int f4 = gu & 15;
            const int su = f4 ^ (k & 15);
            ((float4*)sA1)[k * 16 + su] = *(const float4*)&A1KJ[k * 128 + p * 64 + f4 * 4];
            ((float4*)sA2)[k * 16 + su] = *(const float4*)&A2KJ[k * 128 + p * 64 + f4 * 4];
        }
        __syncthreads();

        #pragma unroll 4
        for (int j4 = 0; j4 < 16; ++j4) {
            const int j = p * 64 + j4 * 4;
            const float4 s1a = *(const float4*)&sh_s[0][i0 + 0][j];
            const float4 s1b = *(const float4*)&sh_s[0][i0 + 1][j];
            const float4 s2a = *(const float4*)&sh_s[1][i0 + 0][j];
            const float4 s2b = *(const float4*)&sh_s[1][i0 + 1][j];
            const float4 w3  = *(const float4*)&sW3[j];
            const int su     = j4 ^ (kk & 15);
            const float4 a1  = ((const float4*)sA1)[kk2 * 16 + su];
            const float4 a2  = ((const float4*)sA2)[kk2 * 16 + su];

            acc0 += (fsigp(s1a.x + a1.x) - fsigp(s2a.x + a2.x)) * w3.x;
            acc0 += (fsigp(s1a.y + a1.y) - fsigp(s2a.y + a2.y)) * w3.y;
            acc0 += (fsigp(s1a.z + a1.z) - fsigp(s2a.z + a2.z)) * w3.z;
            acc0 += (fsigp(s1a.w + a1.w) - fsigp(s2a.w + a2.w)) * w3.w;
            acc1 += (fsigp(s1b.x + a1.x) - fsigp(s2b.x + a2.x)) * w3.x;
            acc1 += (fsigp(s1b.y + a1.y) - fsigp(s2b.y + a2.y)) * w3.y;
            acc1 += (fsigp(s1b.z + a1.z) - fsigp(s2b.z + a2.z)) * w3.z;
            acc1 += (fsigp(s1b.w + a1.w) - fsigp(s2b.w + a2.w)) * w3.w;
        }
    }

    // ---- epilogue: per-k output, kn-weighted mean over k ----
    const float o0  = fsig(acc0 + bb3);
    const float o1  = fsig(acc1 + bb3);
    const float kn0 = kn[(b0 + i0 + 0) * 128 + kk2];
    const float kn1 = kn[(b0 + i0 + 1) * 128 + kk2];
    float co0 = o0 * kn0, ck0 = kn0;
    float co1 = o1 * kn1, ck1 = kn1;
    #pragma unroll
    for (int off = 1; off < 64; off <<= 1) {
        co0 += __shfl_xor(co0, off);
        ck0 += __shfl_xor(ck0, off);
        co1 += __shfl_xor(co1, off);
        ck1 += __shfl_xor(ck1, off);
    }
    if (kk == 0) {
        red_o[w][0] = co0; red_o[w][1] = co1;
        red_k[w][0] = ck0; red_k[w][1] = ck1;
    }
    __syncthreads();
    if (t < 8) {
        const int b  = t;
        const int wl = (b >> 1);          // wave with k-low for this b
        const int i  = b & 1;
        const float so = red_o[wl][i] + red_o[wl + 4][i];
        const float sk = red_k[wl][i] + red_k[wl + 4][i];
        out[b0 + b] = so / sk;
    }
}

// ---------------------------------------------------------------------------
extern "C" void kernel_launch(void* const* d_in, const int* in_sizes, int n_in,
                              void* d_out, int out_size, void* d_ws, size_t ws_size,
                              hipStream_t stream)
{
    const int*   stu_id      = (const int*)  d_in[0];
    const int*   exer_id     = (const int*)  d_in[1];
    const float* kn_emb      = (const float*)d_in[2];
    const float* student_emb = (const float*)d_in[3];
    const float* prompt_stu  = (const float*)d_in[4];
    const float* kle         = (const float*)d_in[5];
    const float* k_diff      = (const float*)d_in[6];
    const float* s_exer      = (const float*)d_in[7];
    const float* W1          = (const float*)d_in[8];
    const float* W2          = (const float*)d_in[9];
    const float* W3          = (const float*)d_in[10];
    const float* b3          = (const float*)d_in[11];
    const float* fc1_W       = (const float*)d_in[12];
    const float* fc1_b       = (const float*)d_in[13];
    const float* fc2_W       = (const float*)d_in[14];
    const float* fc2_b       = (const float*)d_in[15];
    float* out = (float*)d_out;

    float* ws   = (float*)d_ws;
    float* kle4 = ws;                        // 16*128*4  = 8192
    float* fc1i = kle4 + 8192;               // 48*128*4  = 24576
    float* fc2i = fc1i + 24576;
    float* W1ai = fc2i + 24576;              // 32*128*4  = 16384
    float* W2ai = W1ai + 16384;
    float* A1KJ = W2ai + 16384;              // 128*128
    float* A2KJ = A1KJ + 16384;

    k_pre<<<432, 128, 0, stream>>>(kle, W1, W2, fc1_W, fc2_W,
                                   kle4, fc1i, fc2i, W1ai, W2ai, A1KJ, A2KJ);
    k_fused<<<BATCH / 8, 512, 0, stream>>>(stu_id, exer_id, student_emb, prompt_stu,
                                           k_diff, s_exer, kle4, fc1i, fc2i,
                                           W1ai, W2ai, fc1_b, fc2_b,
                                           A1KJ, A2KJ, W3, b3, kn_emb, out);
}